// Round 5
// baseline (63.449 us; speedup 1.0000x reference)
//
#include <hip/hip_runtime.h>

#define NB 128
#define NC 16
#define NT 16384
#define NW 4096
#define TPB 256
#define SPAN 480            // LDS row length (floats); covers max 454-float tap span

typedef float f32x4 __attribute__((ext_vector_type(4)));

// One block = (sample b, 256 consecutive outputs t0..t0+255), all 16 channels.
// Max source-position slope: (L-1)/(T-1) * (W-1)/(nl-1) = 1.7504 (nl=2048 case),
// so 255 t-steps span <= 447 source samples; +2 (qhi tap) +1 (hi) +3 (align) < 480.
__global__ __launch_bounds__(256) void rww_kernel(
    const float* __restrict__ x,
    const int* __restrict__ window_starts,
    const int* __restrict__ new_len,
    float* __restrict__ out)
{
    __shared__ float lds[NC][SPAN];

    const int b  = blockIdx.y;
    const int t0 = blockIdx.x * TPB;
    const int t  = t0 + threadIdx.x;

    const int s  = window_starts[b];
    const int nl = new_len[b];
    const float sf  = (float)s;
    const float nlf = (float)nl;
    const float den = fmaxf(nlf - 1.0f, 1.0f);
    const int   L   = NT + nl - NW;
    const float Lf  = (float)L;

    // ---- block-uniform window start (from t0, exact same float path) ----
    int winstart;
    {
        float qpos = (float)t0 * (Lf - 1.0f) / (float)(NT - 1);
        int   ql   = (int)floorf(qpos);
        float jf   = (float)ql;
        float pos;
        if (jf >= sf + nlf)      pos = jf - nlf + (float)NW;
        else if (jf >= sf)       pos = sf + (jf - sf) * (float)(NW - 1) / den;
        else                     pos = jf;
        pos = fminf(fmaxf(pos, 0.0f), (float)(NT - 1));
        winstart = ((int)floorf(pos)) & ~3;           // 16B-aligned source offset
        winstart = min(winstart, NT - SPAN);
        if (winstart < 0) winstart = 0;
    }

    // ---- stage 16 x 480 floats into LDS with coalesced float4 loads ----
    const float* xb = x + (size_t)b * NC * NT;
    #pragma unroll
    for (int it = 0; it < (NC * SPAN / 4 + TPB - 1) / TPB; ++it) {
        int idx = it * TPB + threadIdx.x;             // 0 .. 1919
        if (idx < NC * (SPAN / 4)) {
            int c   = idx / (SPAN / 4);
            int col = (idx % (SPAN / 4)) * 4;
            f32x4 v = *(const f32x4*)(xb + c * NT + winstart + col);
            *(f32x4*)&lds[c][col] = v;
        }
    }
    __syncthreads();

    // ---- per-thread positions (identical arithmetic to the passing kernel) ----
    float qpos = (float)t * (Lf - 1.0f) / (float)(NT - 1);
    int   qlo  = (int)floorf(qpos);
    int   qhi  = min(qlo + 1, L - 1);
    float qf   = qpos - (float)qlo;

    int r0lo, r0hi, r1lo, r1hi;
    float f0, f1;
    {
        float jf = (float)qlo;
        float pos;
        if (jf >= sf + nlf)      pos = jf - nlf + (float)NW;
        else if (jf >= sf)       pos = sf + (jf - sf) * (float)(NW - 1) / den;
        else                     pos = jf;
        pos = fminf(fmaxf(pos, 0.0f), (float)(NT - 1));
        int lo = (int)floorf(pos);
        int hi = min(lo + 1, NT - 1);
        f0   = pos - (float)lo;
        r0lo = lo - winstart;
        r0hi = hi - winstart;
    }
    {
        float jf = (float)qhi;
        float pos;
        if (jf >= sf + nlf)      pos = jf - nlf + (float)NW;
        else if (jf >= sf)       pos = sf + (jf - sf) * (float)(NW - 1) / den;
        else                     pos = jf;
        pos = fminf(fmaxf(pos, 0.0f), (float)(NT - 1));
        int lo = (int)floorf(pos);
        int hi = min(lo + 1, NT - 1);
        f1   = pos - (float)lo;
        r1lo = lo - winstart;
        r1hi = hi - winstart;
    }

    const float g0 = 1.0f - f0;
    const float g1 = 1.0f - f1;
    const float gq = 1.0f - qf;

    float* ob = out + (size_t)b * NC * NT + t;

    #pragma unroll
    for (int c = 0; c < NC; ++c) {
        float a0 = lds[c][r0lo];
        float b0 = lds[c][r0hi];
        float a1 = lds[c][r1lo];
        float b1 = lds[c][r1hi];
        float v0 = a0 * g0 + b0 * f0;    // warped[qlo]
        float v1 = a1 * g1 + b1 * f1;    // warped[qhi]
        __builtin_nontemporal_store(v0 * gq + v1 * qf, ob + c * NT);
    }
}

extern "C" void kernel_launch(void* const* d_in, const int* in_sizes, int n_in,
                              void* d_out, int out_size, void* d_ws, size_t ws_size,
                              hipStream_t stream) {
    const float* x   = (const float*)d_in[0];
    const int*   ws  = (const int*)d_in[1];
    const int*   nl  = (const int*)d_in[2];
    float*       out = (float*)d_out;

    dim3 grid(NT / TPB, NB);
    dim3 block(TPB);
    rww_kernel<<<grid, block, 0, stream>>>(x, ws, nl, out);
}

// Round 6
// 49.385 us; speedup vs baseline: 1.2848x; 1.2848x over previous
//
#include <hip/hip_runtime.h>

#define NB 128
#define NC 16
#define NT 16384
#define NW 4096

__global__ __launch_bounds__(256) void rww_kernel(
    const float* __restrict__ x,
    const int* __restrict__ window_starts,
    const int* __restrict__ new_len,
    float* __restrict__ out)
{
    const int b = blockIdx.y;
    const int t = blockIdx.x * 256 + threadIdx.x;

    const int s  = window_starts[b];
    const int nl = new_len[b];
    const float sf  = (float)s;
    const float nlf = (float)nl;
    const int   L   = NT + nl - NW;
    const float Lf  = (float)L;

    // Stage 2 query position: q = t*(L-1)/(T-1)
    float qpos = (float)t * (Lf - 1.0f) / (float)(NT - 1);
    int   qlo  = (int)floorf(qpos);
    int   qhi  = min(qlo + 1, L - 1);
    float qf   = qpos - (float)qlo;
    const float gq = 1.0f - qf;

    const float* xb = x   + (size_t)b * NC * NT;
    float*       ob = out + (size_t)b * NC * NT;

    // Fast path: both taps strictly outside the warp window -> pos is exact
    // (f=0), so each warped tap is a single source sample. Bit-identical to
    // the general path (which would multiply by f=0 / g=1 exactly).
    if (qhi < s) {
        // before window: pos = j
        #pragma unroll
        for (int c = 0; c < NC; ++c) {
            const float* xc = xb + c * NT;
            float r = xc[qlo] * gq + xc[qhi] * qf;
            __builtin_nontemporal_store(r, ob + c * NT + t);
        }
        return;
    }
    if ((float)qlo >= sf + nlf) {
        // after window: pos = j - nl + W (exact integer)
        const int off = NW - nl;
        #pragma unroll
        for (int c = 0; c < NC; ++c) {
            const float* xc = xb + c * NT;
            float r = xc[qlo + off] * gq + xc[qhi + off] * qf;
            __builtin_nontemporal_store(r, ob + c * NT + t);
        }
        return;
    }

    // General path (window / straddle): 4-tap
    const float den = fmaxf(nlf - 1.0f, 1.0f);
    int lo0, hi0, lo1, hi1;
    float f0, f1;
    {
        float jf = (float)qlo;
        float pos;
        if (jf >= sf + nlf)      pos = jf - nlf + (float)NW;
        else if (jf >= sf)       pos = sf + (jf - sf) * (float)(NW - 1) / den;
        else                     pos = jf;
        pos = fminf(fmaxf(pos, 0.0f), (float)(NT - 1));
        lo0 = (int)floorf(pos);
        hi0 = min(lo0 + 1, NT - 1);
        f0  = pos - (float)lo0;
    }
    {
        float jf = (float)qhi;
        float pos;
        if (jf >= sf + nlf)      pos = jf - nlf + (float)NW;
        else if (jf >= sf)       pos = sf + (jf - sf) * (float)(NW - 1) / den;
        else                     pos = jf;
        pos = fminf(fmaxf(pos, 0.0f), (float)(NT - 1));
        lo1 = (int)floorf(pos);
        hi1 = min(lo1 + 1, NT - 1);
        f1  = pos - (float)lo1;
    }

    const float g0 = 1.0f - f0;
    const float g1 = 1.0f - f1;

    #pragma unroll
    for (int c = 0; c < NC; ++c) {
        const float* xc = xb + c * NT;
        float v0 = xc[lo0] * g0 + xc[hi0] * f0;   // warped[qlo]
        float v1 = xc[lo1] * g1 + xc[hi1] * f1;   // warped[qhi]
        __builtin_nontemporal_store(v0 * gq + v1 * qf, ob + c * NT + t);
    }
}

extern "C" void kernel_launch(void* const* d_in, const int* in_sizes, int n_in,
                              void* d_out, int out_size, void* d_ws, size_t ws_size,
                              hipStream_t stream) {
    const float* x   = (const float*)d_in[0];
    const int*   ws  = (const int*)d_in[1];
    const int*   nl  = (const int*)d_in[2];
    float*       out = (float*)d_out;

    dim3 grid(NT / 256, NB);
    dim3 block(256);
    rww_kernel<<<grid, block, 0, stream>>>(x, ws, nl, out);
}